// Round 2
// baseline (90.974 us; speedup 1.0000x reference)
//
#include <hip/hip_runtime.h>

// Problem constants (reference: B, T, H, L = 32, 100, 128, 64)
#define BB 32
#define TT 100
#define HH 128

// Mathematical simplification (exact, not approximate):
//   log_softmax over a size-1 axis == 0 exactly  =>  beta == 0  =>  ctx == 0
//   at every scan step (reference comment admits this). Hence:
//     - encoder (x, W_ih_e, b_e, att_*) is dead code
//     - h_s after the scan depends ONLY on d[:, T-2]:
//         din = d[:,T-2] * dec_w[0,0] + dec_b
//         z   = din * W_ih_d[:,0] + b_d          (gate order i,f,g,o; f dead: c0=0)
//         c   = sigmoid(z_i) * tanh(z_g)
//         h   = sigmoid(z_o) * tanh(c)
//     - feat = [h, 0]  => only d1_w[:, :H] used
//     - out[b] = sum_j (dot(h, d1_w[j,:H]) + d1_b[j]) * d2_w[j] + d2_b
//
// All tensors are float32 per the reference source (R0->R1 lesson: the test
// label string says "bf16" unconditionally; actual dtype follows reference).

__global__ __launch_bounds__(HH) void DSA_43722767073506_kernel(
    const float* __restrict__ d,      // (B, T-1)
    const float* __restrict__ W_ih_d, // (4H, 1)
    const float* __restrict__ b_d,    // (4H,)
    const float* __restrict__ dec_w,  // (1, H+1) -> only [0]
    const float* __restrict__ dec_b,  // (1,)
    const float* __restrict__ d1_w,   // (H, 2H) -> only cols [0,H)
    const float* __restrict__ d1_b,   // (H,)
    const float* __restrict__ d2_w,   // (1, H)
    const float* __restrict__ d2_b,   // (1,)
    float* __restrict__ out)          // (B,)
{
    const int b = blockIdx.x;   // batch element
    const int j = threadIdx.x;  // hidden unit

    __shared__ float hs[HH];
    __shared__ float wsum[2];

    // decoder input scalar for the LAST scan step (d[:, T-2])
    const float din = d[b * (TT - 1) + (TT - 2)] * dec_w[0] + dec_b[0];

    // LSTM cell from zero state, input size 1 (W_ih_d is a column vector)
    const float zi = din * W_ih_d[0 * HH + j] + b_d[0 * HH + j];
    const float zg = din * W_ih_d[2 * HH + j] + b_d[2 * HH + j];
    const float zo = din * W_ih_d[3 * HH + j] + b_d[3 * HH + j];
    const float si = 1.0f / (1.0f + expf(-zi));
    const float so = 1.0f / (1.0f + expf(-zo));
    const float c  = si * tanhf(zg);
    const float h  = so * tanhf(c);
    hs[j] = h;
    __syncthreads();

    // hidden[j] = dot(h, d1_w[j, :H]) + d1_b[j];  contrib = hidden * d2_w[j]
    const float* __restrict__ row = d1_w + (size_t)j * (2 * HH);
    float dot = 0.0f;
    #pragma unroll 8
    for (int k = 0; k < HH; ++k)
        dot = fmaf(hs[k], row[k], dot);
    float contrib = (dot + d1_b[j]) * d2_w[j];

    // reduce across the block (2 waves of 64): wave butterfly then LDS combine
    #pragma unroll
    for (int off = 32; off > 0; off >>= 1)
        contrib += __shfl_down(contrib, off, 64);
    if ((j & 63) == 0) wsum[j >> 6] = contrib;
    __syncthreads();
    if (j == 0)
        out[b] = wsum[0] + wsum[1] + d2_b[0];
}

extern "C" void kernel_launch(void* const* d_in, const int* in_sizes, int n_in,
                              void* d_out, int out_size, void* d_ws, size_t ws_size,
                              hipStream_t stream) {
    // setup_inputs() order:
    // 0:x 1:d 2:W_ih_e 3:b_e 4:W_ih_d 5:b_d 6:att_w1 7:att_b1 8:att_w2
    // 9:att_b2 10:att_v 11:att_vb 12:dec_w 13:dec_b 14:d1_w 15:d1_b 16:d2_w 17:d2_b
    const float* d_     = (const float*)d_in[1];
    const float* W_ih_d = (const float*)d_in[4];
    const float* b_d    = (const float*)d_in[5];
    const float* dec_w  = (const float*)d_in[12];
    const float* dec_b  = (const float*)d_in[13];
    const float* d1_w   = (const float*)d_in[14];
    const float* d1_b   = (const float*)d_in[15];
    const float* d2_w   = (const float*)d_in[16];
    const float* d2_b   = (const float*)d_in[17];
    float* out = (float*)d_out;

    DSA_43722767073506_kernel<<<BB, HH, 0, stream>>>(
        d_, W_ih_d, b_d, dec_w, dec_b, d1_w, d1_b, d2_w, d2_b, out);
}